// Round 1
// baseline (36609.204 us; speedup 1.0000x reference)
//
#include <hip/hip_runtime.h>
#include <hip/hip_bf16.h>
#include <cstdint>
#include <cstddef>

// Problem sizes (fixed)
#define BB 64
#define SS 1024
#define II 1024
#define HH 1024
#define G3 3072   // 3*HH

typedef float  f32x4  __attribute__((ext_vector_type(4)));
typedef short  bf16x8 __attribute__((ext_vector_type(8)));

__device__ __forceinline__ unsigned short f2b(float f) {
    unsigned u = __float_as_uint(f);
    u += 0x7FFFu + ((u >> 16) & 1u);   // RNE
    return (unsigned short)(u >> 16);
}
__device__ __forceinline__ float b2f(unsigned short s) {
    return __uint_as_float(((unsigned)s) << 16);
}

// ---------------------------------------------------------------------------
// Kernel 1: gi = x @ W_ih^T + b_ih      (M=B*S=65536, K=1024, N=3072)
// 128x128 tile, 4 waves, reg-staged fp32->bf16 conversion into LDS,
// mfma_f32_16x16x32_bf16, fp32 (or bf16) output to workspace.
// ---------------------------------------------------------------------------
template<int GI_BF16>
__global__ __launch_bounds__(256)
void gi_gemm(const float* __restrict__ X, const float* __restrict__ W,
             const float* __restrict__ bias, void* __restrict__ gi_out)
{
    __shared__ short As[128][40];   // +8 pad breaks bank conflicts
    __shared__ short Bs[128][40];

    const int t    = threadIdx.x;
    const int lane = t & 63;
    const int wave = t >> 6;
    const int m0   = blockIdx.y * 128;
    const int n0   = blockIdx.x * 128;

    f32x4 acc[4][4] = {};

    for (int k0 = 0; k0 < II; k0 += 32) {
        __syncthreads();
        // stage 128x32 of A (x) and B (W_ih), converting fp32->bf16
        #pragma unroll
        for (int q = 0; q < 4; ++q) {
            int row = (t >> 3) + 32 * q;
            int col = (t & 7) * 4;
            const float4 a = *reinterpret_cast<const float4*>(X + (size_t)(m0 + row) * II + k0 + col);
            const float4 b = *reinterpret_cast<const float4*>(W + (size_t)(n0 + row) * II + k0 + col);
            As[row][col + 0] = (short)f2b(a.x); As[row][col + 1] = (short)f2b(a.y);
            As[row][col + 2] = (short)f2b(a.z); As[row][col + 3] = (short)f2b(a.w);
            Bs[row][col + 0] = (short)f2b(b.x); Bs[row][col + 1] = (short)f2b(b.y);
            Bs[row][col + 2] = (short)f2b(b.z); Bs[row][col + 3] = (short)f2b(b.w);
        }
        __syncthreads();

        const int mb = (wave & 1) * 64;
        const int nb = (wave >> 1) * 64;
        bf16x8 af[4], bf[4];
        #pragma unroll
        for (int i = 0; i < 4; ++i) {
            af[i] = *reinterpret_cast<const bf16x8*>(&As[mb + i * 16 + (lane & 15)][(lane >> 4) * 8]);
            bf[i] = *reinterpret_cast<const bf16x8*>(&Bs[nb + i * 16 + (lane & 15)][(lane >> 4) * 8]);
        }
        #pragma unroll
        for (int mi = 0; mi < 4; ++mi)
            #pragma unroll
            for (int ni = 0; ni < 4; ++ni)
                acc[mi][ni] = __builtin_amdgcn_mfma_f32_16x16x32_bf16(af[mi], bf[ni], acc[mi][ni], 0, 0, 0);
    }

    // epilogue: add bias, store
    const int mb = (wave & 1) * 64;
    const int nb = (wave >> 1) * 64;
    #pragma unroll
    for (int ni = 0; ni < 4; ++ni) {
        int ncol = n0 + nb + ni * 16 + (lane & 15);
        float bv = bias[ncol];
        #pragma unroll
        for (int mi = 0; mi < 4; ++mi) {
            int mrow = m0 + mb + mi * 16 + ((lane >> 4) << 2);
            #pragma unroll
            for (int e = 0; e < 4; ++e) {
                float v = acc[mi][ni][e] + bv;
                size_t idx = (size_t)(mrow + e) * G3 + ncol;
                if (GI_BF16) ((unsigned short*)gi_out)[idx] = f2b(v);
                else         ((float*)gi_out)[idx] = v;
            }
        }
    }
}

// ---------------------------------------------------------------------------
// Kernel 2: init  (reset flags, h16[buf0] = bf16(h0))
// ---------------------------------------------------------------------------
__global__ __launch_bounds__(256)
void gru_init(const float* __restrict__ h0, unsigned short* __restrict__ h16,
              int* __restrict__ flags)
{
    int i = blockIdx.x * 256 + threadIdx.x;
    if (i < BB * HH) h16[i] = f2b(h0[i]);
    if (i < 256)     flags[i] = 0;
}

// ---------------------------------------------------------------------------
// Kernel 3: the sequential scan. Cooperative, 256 blocks x 256 threads.
// Block bid: group = bid&3 (16 batches), jb = bid>>2 (16 j-columns, 48 W rows).
// W_hh slice lives in registers as 8(kc) x 3(gate) pre-packed B-fragments.
// Per step: MFMA M=16,N=48,K=1024 (K split across 4 waves, LDS reduce),
// gates in fp32, h kept double-buffered bf16 in ws, group-local flag sync.
// ---------------------------------------------------------------------------
template<int GI_BF16>
__global__ __launch_bounds__(256)
void gru_scan(const void* __restrict__ gi_v, const float* __restrict__ Whh,
              const float* __restrict__ h0, unsigned short* __restrict__ h16,
              int* __restrict__ flags, float* __restrict__ out)
{
    const int t     = threadIdx.x;
    const int lane  = t & 63;
    const int wave  = t >> 6;
    const int bid   = blockIdx.x;
    const int group = bid & 3;    // consecutive bids -> different groups (XCD spread)
    const int jb    = bid >> 2;

    __shared__ f32x4 part[4][3][64];  // [wave][gate][lane]
    __shared__ float gh[16][48];      // [batch][3*16 gate cols]

    // ---- one-time: preload W_hh slice as MFMA B-fragments (96 VGPR) ----
    bf16x8 wf[8][3];
    #pragma unroll
    for (int kc = 0; kc < 8; ++kc) {
        #pragma unroll
        for (int nt = 0; nt < 3; ++nt) {
            int rowg = nt * HH + jb * 16 + (lane & 15);
            int k    = wave * 256 + kc * 32 + ((lane >> 4) << 3);
            const float4* src = reinterpret_cast<const float4*>(Whh + (size_t)rowg * HH + k);
            float4 f0 = src[0], f1 = src[1];
            bf16x8 w;
            w[0] = (short)f2b(f0.x); w[1] = (short)f2b(f0.y);
            w[2] = (short)f2b(f0.z); w[3] = (short)f2b(f0.w);
            w[4] = (short)f2b(f1.x); w[5] = (short)f2b(f1.y);
            w[6] = (short)f2b(f1.z); w[7] = (short)f2b(f1.w);
            wf[kc][nt] = w;
        }
    }

    const int b_l = t >> 4, j_l = t & 15;
    const int b_g = (group << 4) + b_l;     // global batch of this thread's gate slot
    const int j_g = (jb << 4) + j_l;        // global hidden index
    float hreg = h0[b_g * HH + j_g];        // h_old lives in a register forever

    const int arow = (group << 4) + (lane & 15);  // batch row this lane reads for A-frags

    for (int s = 0; s < SS; ++s) {
        const int p = s & 1;

        // prefetch gi (independent of h — issues before the poll)
        size_t gib = ((size_t)b_g * SS + s) * G3;
        float ir, iz, inn;
        if (GI_BF16) {
            const unsigned short* g16 = (const unsigned short*)gi_v;
            ir  = b2f(g16[gib + j_g]);
            iz  = b2f(g16[gib + HH + j_g]);
            inn = b2f(g16[gib + 2 * HH + j_g]);
        } else {
            const float* g32 = (const float*)gi_v;
            ir  = g32[gib + j_g];
            iz  = g32[gib + HH + j_g];
            inn = g32[gib + 2 * HH + j_g];
        }

        // wait until every block in this group finished step s-1
        if (s > 0) {
            if (wave == 0) {
                const int idx = (group << 6) | lane;   // 64 flags, one per lane
                while (true) {
                    int v = __hip_atomic_load(&flags[idx], __ATOMIC_ACQUIRE,
                                              __HIP_MEMORY_SCOPE_AGENT);
                    if (__all(v >= s)) break;
                    __builtin_amdgcn_s_sleep(4);
                }
            }
            __syncthreads();
        }

        // ---- gh = h @ W_hh^T (this block's 48 columns), K split over waves ----
        f32x4 a0 = {0,0,0,0}, a1 = {0,0,0,0}, a2 = {0,0,0,0};
        const unsigned short* hb = h16 + (size_t)p * (BB * HH) + (size_t)arow * HH;
        #pragma unroll
        for (int kc = 0; kc < 8; ++kc) {
            int k = wave * 256 + kc * 32 + ((lane >> 4) << 3);
            bf16x8 af = *reinterpret_cast<const bf16x8*>(hb + k);
            a0 = __builtin_amdgcn_mfma_f32_16x16x32_bf16(af, wf[kc][0], a0, 0, 0, 0);
            a1 = __builtin_amdgcn_mfma_f32_16x16x32_bf16(af, wf[kc][1], a1, 0, 0, 0);
            a2 = __builtin_amdgcn_mfma_f32_16x16x32_bf16(af, wf[kc][2], a2, 0, 0, 0);
        }
        part[wave][0][lane] = a0;
        part[wave][1][lane] = a1;
        part[wave][2][lane] = a2;
        __syncthreads();

        if (t < 192) {  // cross-wave K reduction, scatter to [batch][col]
            int nt = t >> 6, l2 = t & 63;
            f32x4 sv = part[0][nt][l2] + part[1][nt][l2] + part[2][nt][l2] + part[3][nt][l2];
            int col = nt * 16 + (l2 & 15);
            int br  = (l2 >> 4) << 2;
            gh[br + 0][col] = sv[0];
            gh[br + 1][col] = sv[1];
            gh[br + 2][col] = sv[2];
            gh[br + 3][col] = sv[3];
        }
        __syncthreads();

        // ---- gates (each thread owns one (batch, j) slot) ----
        float hr = gh[b_l][j_l], hz = gh[b_l][16 + j_l], hn = gh[b_l][32 + j_l];
        float r = 1.f / (1.f + __expf(-(ir + hr)));
        float z = 1.f / (1.f + __expf(-(iz + hz)));
        float n = tanhf(inn + r * hn);
        float hnew = (1.f - z) * n + z * hreg;
        hreg = hnew;

        out[((size_t)b_g * SS + s) * HH + j_g] = hnew;
        h16[(size_t)(p ^ 1) * (BB * HH) + (size_t)b_g * HH + j_g] = f2b(hnew);

        __threadfence();     // device-scope: make h16 writes visible cross-XCD
        __syncthreads();
        if (t == 0)
            __hip_atomic_store(&flags[(group << 6) | jb], s + 1, __ATOMIC_RELEASE,
                               __HIP_MEMORY_SCOPE_AGENT);
    }

    // final hidden state
    out[(size_t)BB * SS * HH + (size_t)b_g * HH + j_g] = hreg;
}

// ---------------------------------------------------------------------------
// Host launcher
// ---------------------------------------------------------------------------
extern "C" void kernel_launch(void* const* d_in, const int* in_sizes, int n_in,
                              void* d_out, int out_size, void* d_ws, size_t ws_size,
                              hipStream_t stream)
{
    const float* x   = (const float*)d_in[0];
    const float* h0  = (const float*)d_in[1];
    const float* Wih = (const float*)d_in[2];
    const float* Whh = (const float*)d_in[3];
    const float* bih = (const float*)d_in[4];
    float* out = (float*)d_out;

    char* ws = (char*)d_ws;
    unsigned short* h16 = (unsigned short*)ws;               // 2 * 64 * 1024 * 2B = 256 KiB
    int* flags          = (int*)(ws + 262144);               // 256 * 4B
    void* gi            = (void*)(ws + (1 << 20));           // 1 MiB offset, aligned

    const size_t gi32_bytes = (size_t)BB * SS * G3 * 4;      // 768 MiB
    const size_t gi16_bytes = gi32_bytes / 2;                // 384 MiB
    const bool use_f32 = ws_size >= ((size_t)(1 << 20) + gi32_bytes);
    const bool use_b16 = !use_f32 && ws_size >= ((size_t)(1 << 20) + gi16_bytes);
    if (!use_f32 && !use_b16) return;   // workspace too small — would OOB; bail

    gru_init<<<dim3(256), dim3(256), 0, stream>>>(h0, h16, flags);

    const void* gi_c = gi;
    const float* Whh_c = Whh;
    const float* h0_c = h0;
    unsigned short* h16_c = h16;
    int* flags_c = flags;
    float* out_c = out;
    void* args[] = { (void*)&gi_c, (void*)&Whh_c, (void*)&h0_c,
                     (void*)&h16_c, (void*)&flags_c, (void*)&out_c };

    if (use_f32) {
        gi_gemm<0><<<dim3(24, 512), dim3(256), 0, stream>>>(x, Wih, bih, gi);
        hipLaunchCooperativeKernel((const void*)&gru_scan<0>, dim3(256), dim3(256),
                                   args, 0, stream);
    } else {
        gi_gemm<1><<<dim3(24, 512), dim3(256), 0, stream>>>(x, Wih, bih, gi);
        hipLaunchCooperativeKernel((const void*)&gru_scan<1>, dim3(256), dim3(256),
                                   args, 0, stream);
    }
}

// Round 2
// 5281.893 us; speedup vs baseline: 6.9311x; 6.9311x over previous
//
#include <hip/hip_runtime.h>
#include <hip/hip_bf16.h>
#include <cstdint>
#include <cstddef>

// Problem sizes (fixed)
#define BB 64
#define SS 1024
#define II 1024
#define HH 1024
#define G3 3072   // 3*HH

typedef float  f32x4  __attribute__((ext_vector_type(4)));
typedef short  bf16x8 __attribute__((ext_vector_type(8)));

__device__ __forceinline__ unsigned short f2b(float f) {
    unsigned u = __float_as_uint(f);
    u += 0x7FFFu + ((u >> 16) & 1u);   // RNE
    return (unsigned short)(u >> 16);
}
__device__ __forceinline__ float b2f(unsigned short s) {
    return __uint_as_float(((unsigned)s) << 16);
}

// ---------------------------------------------------------------------------
// Kernel 1: gi = x @ W_ih^T + b_ih      (M=B*S=65536, K=1024, N=3072)
// 128x128 tile, 4 waves, reg-staged fp32->bf16 conversion into LDS,
// mfma_f32_16x16x32_bf16, fp32 (or bf16) output to workspace.
// ---------------------------------------------------------------------------
template<int GI_BF16>
__global__ __launch_bounds__(256)
void gi_gemm(const float* __restrict__ X, const float* __restrict__ W,
             const float* __restrict__ bias, void* __restrict__ gi_out)
{
    __shared__ short As[128][40];   // +8 pad breaks bank conflicts
    __shared__ short Bs[128][40];

    const int t    = threadIdx.x;
    const int lane = t & 63;
    const int wave = t >> 6;
    const int m0   = blockIdx.y * 128;
    const int n0   = blockIdx.x * 128;

    f32x4 acc[4][4] = {};

    for (int k0 = 0; k0 < II; k0 += 32) {
        __syncthreads();
        // stage 128x32 of A (x) and B (W_ih), converting fp32->bf16
        #pragma unroll
        for (int q = 0; q < 4; ++q) {
            int row = (t >> 3) + 32 * q;
            int col = (t & 7) * 4;
            const float4 a = *reinterpret_cast<const float4*>(X + (size_t)(m0 + row) * II + k0 + col);
            const float4 b = *reinterpret_cast<const float4*>(W + (size_t)(n0 + row) * II + k0 + col);
            As[row][col + 0] = (short)f2b(a.x); As[row][col + 1] = (short)f2b(a.y);
            As[row][col + 2] = (short)f2b(a.z); As[row][col + 3] = (short)f2b(a.w);
            Bs[row][col + 0] = (short)f2b(b.x); Bs[row][col + 1] = (short)f2b(b.y);
            Bs[row][col + 2] = (short)f2b(b.z); Bs[row][col + 3] = (short)f2b(b.w);
        }
        __syncthreads();

        const int mb = (wave & 1) * 64;
        const int nb = (wave >> 1) * 64;
        bf16x8 af[4], bf[4];
        #pragma unroll
        for (int i = 0; i < 4; ++i) {
            af[i] = *reinterpret_cast<const bf16x8*>(&As[mb + i * 16 + (lane & 15)][(lane >> 4) * 8]);
            bf[i] = *reinterpret_cast<const bf16x8*>(&Bs[nb + i * 16 + (lane & 15)][(lane >> 4) * 8]);
        }
        #pragma unroll
        for (int mi = 0; mi < 4; ++mi)
            #pragma unroll
            for (int ni = 0; ni < 4; ++ni)
                acc[mi][ni] = __builtin_amdgcn_mfma_f32_16x16x32_bf16(af[mi], bf[ni], acc[mi][ni], 0, 0, 0);
    }

    // epilogue: add bias, store
    const int mb = (wave & 1) * 64;
    const int nb = (wave >> 1) * 64;
    #pragma unroll
    for (int ni = 0; ni < 4; ++ni) {
        int ncol = n0 + nb + ni * 16 + (lane & 15);
        float bv = bias[ncol];
        #pragma unroll
        for (int mi = 0; mi < 4; ++mi) {
            int mrow = m0 + mb + mi * 16 + ((lane >> 4) << 2);
            #pragma unroll
            for (int e = 0; e < 4; ++e) {
                float v = acc[mi][ni][e] + bv;
                size_t idx = (size_t)(mrow + e) * G3 + ncol;
                if (GI_BF16) ((unsigned short*)gi_out)[idx] = f2b(v);
                else         ((float*)gi_out)[idx] = v;
            }
        }
    }
}

// ---------------------------------------------------------------------------
// Kernel 2: init  (reset flags, h16[buf0] = bf16(h0))
// ---------------------------------------------------------------------------
__global__ __launch_bounds__(256)
void gru_init(const float* __restrict__ h0, unsigned short* __restrict__ h16,
              int* __restrict__ flags)
{
    int i = blockIdx.x * 256 + threadIdx.x;
    if (i < BB * HH) h16[i] = f2b(h0[i]);
    if (i < 256)     flags[i] = 0;
}

// ---------------------------------------------------------------------------
// Kernel 3: sequential scan. Cooperative, 256 blocks x 256 threads.
// group = bid&3 (16 batches), jb = bid>>2 (16 j-columns -> 48 W_hh rows).
// W_hh slice in registers (24 pre-packed B-frags). Per step:
// MFMA M=16,N=48,K=1024 (K split over 4 waves, LDS+direct-gather reduce).
// Cross-block handoff is FENCE-FREE: all shared state (h16, flags) moves via
// relaxed agent-scope (sc1, L2-bypass) atomics; producer release is a plain
// s_waitcnt vmcnt(0) (sc1 stores are acked at the device coherence point).
// No buffer_inv / buffer_wbl2 is ever emitted in the loop.
// ---------------------------------------------------------------------------
template<int GI_BF16>
__global__ __launch_bounds__(256)
void gru_scan(const void* __restrict__ gi_v, const float* __restrict__ Whh,
              const float* __restrict__ h0, unsigned short* __restrict__ h16,
              int* __restrict__ flags, float* __restrict__ out)
{
    const int t     = threadIdx.x;
    const int lane  = t & 63;
    const int wave  = t >> 6;
    const int bid   = blockIdx.x;
    const int group = bid & 3;
    const int jb    = bid >> 2;

    __shared__ f32x4 part[4][3][64];  // [wave][gate][lane]

    // ---- one-time: preload W_hh slice as MFMA B-fragments (96 VGPR) ----
    bf16x8 wf[8][3];
    #pragma unroll
    for (int kc = 0; kc < 8; ++kc) {
        #pragma unroll
        for (int nt = 0; nt < 3; ++nt) {
            int rowg = nt * HH + jb * 16 + (lane & 15);
            int k    = wave * 256 + kc * 32 + ((lane >> 4) << 3);
            const float4* src = reinterpret_cast<const float4*>(Whh + (size_t)rowg * HH + k);
            float4 f0 = src[0], f1 = src[1];
            bf16x8 w;
            w[0] = (short)f2b(f0.x); w[1] = (short)f2b(f0.y);
            w[2] = (short)f2b(f0.z); w[3] = (short)f2b(f0.w);
            w[4] = (short)f2b(f1.x); w[5] = (short)f2b(f1.y);
            w[6] = (short)f2b(f1.z); w[7] = (short)f2b(f1.w);
            wf[kc][nt] = w;
        }
    }

    const int b_l = t >> 4, j_l = t & 15;
    const int b_g = (group << 4) + b_l;     // global batch of this thread's gate slot
    const int j_g = (jb << 4) + j_l;        // global hidden index
    float hreg = h0[b_g * HH + j_g];        // h_old lives in a register forever

    const int arow = (group << 4) + (lane & 15);  // batch row for A-frags
    const int kbase = wave * 256 + ((lane >> 4) << 3);

    for (int s = 0; s < SS; ++s) {
        const int p = s & 1;

        // prefetch gi (independent of h — issues before the poll)
        size_t gib = ((size_t)b_g * SS + s) * G3;
        float ir, iz, inn;
        if (GI_BF16) {
            const unsigned short* g16 = (const unsigned short*)gi_v;
            ir  = b2f(g16[gib + j_g]);
            iz  = b2f(g16[gib + HH + j_g]);
            inn = b2f(g16[gib + 2 * HH + j_g]);
        } else {
            const float* g32 = (const float*)gi_v;
            ir  = g32[gib + j_g];
            iz  = g32[gib + HH + j_g];
            inn = g32[gib + 2 * HH + j_g];
        }

        // wait until every block in this group finished step s-1 (RELAXED poll:
        // no buffer_inv storm; sc1 loads read the coherence point directly)
        if (s > 0) {
            if (wave == 0) {
                const int idx = (group << 6) | lane;   // 64 flags, one per lane
                while (true) {
                    int v = __hip_atomic_load(&flags[idx], __ATOMIC_RELAXED,
                                              __HIP_MEMORY_SCOPE_AGENT);
                    if (__all(v >= s)) break;
                    __builtin_amdgcn_s_sleep(1);
                }
                asm volatile("" ::: "memory");   // don't hoist h loads above poll
            }
            __syncthreads();
        }

        // ---- load this wave's h fragments (sc1, L2-bypass), all up front ----
        const unsigned long long* hq =
            (const unsigned long long*)(h16 + (size_t)p * (BB * HH));
        unsigned long long hv[16];
        #pragma unroll
        for (int kc = 0; kc < 8; ++kc) {
            size_t qi = ((size_t)arow * HH + kbase + kc * 32) >> 2;
            hv[2 * kc]     = __hip_atomic_load(hq + qi,     __ATOMIC_RELAXED,
                                               __HIP_MEMORY_SCOPE_AGENT);
            hv[2 * kc + 1] = __hip_atomic_load(hq + qi + 1, __ATOMIC_RELAXED,
                                               __HIP_MEMORY_SCOPE_AGENT);
        }

        // ---- gh = h @ W_hh^T (this block's 48 columns), K split over waves ----
        f32x4 a0 = {0,0,0,0}, a1 = {0,0,0,0}, a2 = {0,0,0,0};
        #pragma unroll
        for (int kc = 0; kc < 8; ++kc) {
            union { unsigned long long q[2]; bf16x8 v; } u;
            u.q[0] = hv[2 * kc]; u.q[1] = hv[2 * kc + 1];
            a0 = __builtin_amdgcn_mfma_f32_16x16x32_bf16(u.v, wf[kc][0], a0, 0, 0, 0);
            a1 = __builtin_amdgcn_mfma_f32_16x16x32_bf16(u.v, wf[kc][1], a1, 0, 0, 0);
            a2 = __builtin_amdgcn_mfma_f32_16x16x32_bf16(u.v, wf[kc][2], a2, 0, 0, 0);
        }
        part[wave][0][lane] = a0;
        part[wave][1][lane] = a1;
        part[wave][2][lane] = a2;
        __syncthreads();

        // ---- cross-wave K reduce merged with gates: each thread gathers its
        //      own (b_l, j_l) partials directly ----
        const int lp = ((b_l >> 2) << 4) | j_l;
        const int e  = b_l & 3;
        float hr = 0.f, hz = 0.f, hn = 0.f;
        #pragma unroll
        for (int w = 0; w < 4; ++w) {
            hr += part[w][0][lp][e];
            hz += part[w][1][lp][e];
            hn += part[w][2][lp][e];
        }

        float r = 1.f / (1.f + __expf(-(ir + hr)));
        float z = 1.f / (1.f + __expf(-(iz + hz)));
        float n = tanhf(inn + r * hn);
        float hnew = (1.f - z) * n + z * hreg;
        hreg = hnew;

        out[((size_t)b_g * SS + s) * HH + j_g] = hnew;

        // ---- publish h (packed bf16 pair, relaxed agent / sc1) ----
        unsigned short myb = f2b(hnew);
        unsigned pv = (unsigned)__shfl_xor((int)(unsigned)myb, 1);
        if ((j_l & 1) == 0) {
            unsigned val = ((unsigned)myb) | (pv << 16);
            unsigned* hw = (unsigned*)(h16 + (size_t)(p ^ 1) * (BB * HH));
            __hip_atomic_store(hw + ((b_g * HH + j_g) >> 1), val,
                               __ATOMIC_RELAXED, __HIP_MEMORY_SCOPE_AGENT);
        }

        // release: sc1 stores ack at coherence point on vmcnt(0); then one flag
        asm volatile("s_waitcnt vmcnt(0)" ::: "memory");
        __syncthreads();
        if (t == 0)
            __hip_atomic_store(&flags[(group << 6) | jb], s + 1,
                               __ATOMIC_RELAXED, __HIP_MEMORY_SCOPE_AGENT);
    }

    // final hidden state
    out[(size_t)BB * SS * HH + (size_t)b_g * HH + j_g] = hreg;
}

// ---------------------------------------------------------------------------
// Host launcher
// ---------------------------------------------------------------------------
extern "C" void kernel_launch(void* const* d_in, const int* in_sizes, int n_in,
                              void* d_out, int out_size, void* d_ws, size_t ws_size,
                              hipStream_t stream)
{
    const float* x   = (const float*)d_in[0];
    const float* h0  = (const float*)d_in[1];
    const float* Wih = (const float*)d_in[2];
    const float* Whh = (const float*)d_in[3];
    const float* bih = (const float*)d_in[4];
    float* out = (float*)d_out;

    char* ws = (char*)d_ws;
    unsigned short* h16 = (unsigned short*)ws;               // 2 * 64 * 1024 * 2B = 256 KiB
    int* flags          = (int*)(ws + 262144);               // 256 * 4B
    void* gi            = (void*)(ws + (1 << 20));           // 1 MiB offset, aligned

    const size_t gi32_bytes = (size_t)BB * SS * G3 * 4;      // 768 MiB
    const size_t gi16_bytes = gi32_bytes / 2;                // 384 MiB
    const bool use_f32 = ws_size >= ((size_t)(1 << 20) + gi32_bytes);
    const bool use_b16 = !use_f32 && ws_size >= ((size_t)(1 << 20) + gi16_bytes);
    if (!use_f32 && !use_b16) return;   // workspace too small — would OOB; bail

    gru_init<<<dim3(256), dim3(256), 0, stream>>>(h0, h16, flags);

    const void* gi_c = gi;
    const float* Whh_c = Whh;
    const float* h0_c = h0;
    unsigned short* h16_c = h16;
    int* flags_c = flags;
    float* out_c = out;
    void* args[] = { (void*)&gi_c, (void*)&Whh_c, (void*)&h0_c,
                     (void*)&h16_c, (void*)&flags_c, (void*)&out_c };

    if (use_f32) {
        gi_gemm<0><<<dim3(24, 512), dim3(256), 0, stream>>>(x, Wih, bih, gi);
        hipLaunchCooperativeKernel((const void*)&gru_scan<0>, dim3(256), dim3(256),
                                   args, 0, stream);
    } else {
        gi_gemm<1><<<dim3(24, 512), dim3(256), 0, stream>>>(x, Wih, bih, gi);
        hipLaunchCooperativeKernel((const void*)&gru_scan<1>, dim3(256), dim3(256),
                                   args, 0, stream);
    }
}